// Round 5
// baseline (788.302 us; speedup 1.0000x reference)
//
#include <hip/hip_runtime.h>

// RoutingCapsule: x(16,2048,16) fp32, W(1,2048,64,32,16) fp32, bias(64,32) fp32
// -> v(16,64,32) fp32.   Routing collapses (b_logits additive from 0):
//   s0 = (1/64) sum_i u ; v0 = squash(s0+bias)
//   pass1: c1 = softmax_o(u.v0)      ; s1 = sum_i c1*u
//   pass2: c2 = softmax_o(u.(v0+v1)) ; out = squash(sum_i c2*u + bias)
//
// R11: occupancy + stall fixes on the R10 no-u structure (630us).
// Budget: ~320us = 2x 1GiB harness poison fills (uncontrollable floor);
// ~310us ours vs ~150us HBM floor (3x W reads + partials).
//  - k_s0sweep: VGPR=40 but bounds(256,4) pinned it to 16 waves/CU and TWO
//    rounds of 2048 blocks. bounds(256,8) -> 8 blocks/CU, ONE round,
//    32 waves/CU latency hiding on the W stream. (biggest suspected laggard)
//  - k_rsweep: 8 fresh global x loads at the top of EVERY i-iteration were a
//    ~200-900cy stall in the critical loop (not hoistable across barriers).
//    x now staged once to LDS (8KB); loop reads are broadcast ds_read + rfl.
//    VGPR (~230: u64+acc64+vv64) caps occupancy at 2 waves/SIMD — structural;
//    A/B half-pipeline already balances LDS (2.6us/half) vs HBM (2.6us/half).
//  - reducers: grid 128 used half the CUs; now 256 blocks x 128 thr.
// Rejected: fp16-u cache (bf16 measured 0.465 absmax; fp16 extrapolates
// ~0.06 >> tol), 4b/wave LDS-halving (384 VGPR), 2-block/CU rsweep (needs
// <=128 VGPR, impossible at 192 state regs).
#define B_ 16
#define I_ 2048
#define OD_ 2048
#define EPSQ 1e-9f

typedef float v4f __attribute__((ext_vector_type(4)));

__device__ __forceinline__ float squashf(float s) {
  float sq = s * s;
  return sq / (1.0f + sq) * s * rsqrtf(sq + EPSQ);
}

__device__ __forceinline__ float dot4(v4f a, v4f b) {
  return a.x * b.x + a.y * b.y + a.z * b.z + a.w * b.w;
}

__device__ __forceinline__ void gload16(const void* g, void* l) {
  __builtin_amdgcn_global_load_lds(
      (__attribute__((address_space(1))) const unsigned int*)g,
      (__attribute__((address_space(3))) unsigned int*)l, 16, 0, 0);
}

__device__ __forceinline__ float rfl(float v) {
  return __uint_as_float(__builtin_amdgcn_readfirstlane(__float_as_uint(v)));
}

// ---------------------------------------------------------------------------
// K1: s0 partials only (no u materialization).
// grid=2048: bx&7 = od-eighth e, bx>>3 = i-chunk ic (8 i each). Thread owns
// od = e*256+t. x staged in LDS; W register double-buffered.
// bounds(256,8): VGPR<=64 (kernel ~40) -> 8 blocks/CU, single round.
// part0[ic][b][od] : 256*16*2048 fp32 = 32 MB.
// ---------------------------------------------------------------------------
__global__ __launch_bounds__(256, 8) void k_s0sweep(
    const float* __restrict__ x, const float* __restrict__ W,
    float* __restrict__ part0)
{
  __shared__ float xs[8 * 16 * 16];  // [ii][b][p] 8 KB
  const int t = threadIdx.x;
  const int e = blockIdx.x & 7;
  const int ic = blockIdx.x >> 3;
  const int i0 = ic * 8;
  const int od = e * 256 + t;

  {
    const int b = t >> 4, j = t & 15;
    const float4* src = (const float4*)(x + (size_t)(b * I_ + i0) * 16);
    float4 a0 = src[j * 2], a1 = src[j * 2 + 1];
    const int ii = j >> 1, pq = (j & 1) * 2;
    float4* dst = (float4*)xs + ii * 64 + b * 4;
    dst[pq] = a0; dst[pq + 1] = a1;
  }
  __syncthreads();

  float s0acc[B_];
#pragma unroll
  for (int b = 0; b < B_; ++b) s0acc[b] = 0.f;

  const v4f* wb = (const v4f*)(W + ((size_t)i0 * OD_ + od) * 16);
  v4f wc[4], wn[4];
#pragma unroll
  for (int k = 0; k < 4; ++k) wc[k] = __builtin_nontemporal_load(wb + k);

  for (int ii = 0; ii < 8; ++ii) {
    if (ii < 7) {
      const v4f* wnp = wb + (size_t)(ii + 1) * 8192;
#pragma unroll
      for (int k = 0; k < 4; ++k) wn[k] = __builtin_nontemporal_load(wnp + k);
    }
    const v4f* xv = (const v4f*)xs + ii * 64;
#pragma unroll
    for (int b = 0; b < B_; ++b) {
      v4f x0 = xv[b * 4 + 0], x1 = xv[b * 4 + 1];
      v4f x2 = xv[b * 4 + 2], x3 = xv[b * 4 + 3];
      s0acc[b] += dot4(x0, wc[0]) + dot4(x1, wc[1]) +
                  dot4(x2, wc[2]) + dot4(x3, wc[3]);
    }
    if (ii < 7) {
#pragma unroll
      for (int k = 0; k < 4; ++k) wc[k] = wn[k];
    }
  }
#pragma unroll
  for (int b = 0; b < B_; ++b)
    part0[((size_t)ic * B_ + b) * OD_ + od] = s0acc[b];
}

// ---------------------------------------------------------------------------
// K2: s0_raw[b,od] = sum_ic part0[ic][b][od].  grid=256 (16 b x 16 slices).
// ---------------------------------------------------------------------------
__global__ __launch_bounds__(128) void k_s0red(
    const float* __restrict__ part0, float* __restrict__ s0)
{
  const int b = blockIdx.x >> 4;
  const int od = (blockIdx.x & 15) * 128 + threadIdx.x;
  float a = 0.f;
  const float* p = part0 + (size_t)b * OD_ + od;
#pragma unroll 8
  for (int ic = 0; ic < 256; ++ic) a += p[(size_t)ic * B_ * OD_];
  s0[b * OD_ + od] = a;
}

// ---------------------------------------------------------------------------
// K3: fused routing sweep — recomputes u from W/x, W streamed exactly once.
// 256 blocks x 512 thr (8 waves, 1 block/CU, LDS 141KB). Block owns 8 i.
// Wave wv owns b = 2wv, 2wv+1; lane = o. Per i: W row staged in two 64KB
// d-halves, double-buffered; x from 8KB LDS (staged once); u kept in regs;
// exact softmax per (b,i); one 8KB partial write per (wave,b).
// part[(b*256 + blk)][od] : 32 MB.
// ---------------------------------------------------------------------------
__global__ __launch_bounds__(512, 2) void k_rsweep(
    const float* __restrict__ x, const float* __restrict__ W,
    const float* __restrict__ sA, float scaleA,
    const float* __restrict__ sB,  // may be null
    const float* __restrict__ bias,
    float* __restrict__ part)
{
  __shared__ float4 bufA[64 * 65];   // 66560 B
  __shared__ float4 bufB[64 * 65];   // 66560 B
  __shared__ float  xls[8 * 16 * 16];  // [ii][b][p] 8 KB
  const int t = threadIdx.x;
  const int o = t & 63;
  const int wv = t >> 6;
  const int i0 = blockIdx.x * 8;

  // stage x[b, i0..i0+7, :] -> xls[ii][b][p]; identity-linear f4 mapping.
  {
    const int ii = t >> 6, b = (t >> 2) & 15, q = t & 3;
    ((float4*)xls)[ii * 64 + b * 4 + q] =
        ((const float4*)x)[(size_t)b * (I_ * 4) + (size_t)(i0 + ii) * 4 + q];
  }

  // vv = squash(sA*scaleA + bias) [+ squash(sB + bias)], per (bb, d)
  float vvA[2][16], vvB[2][16];
#pragma unroll
  for (int bb = 0; bb < 2; ++bb) {
    const int b = wv * 2 + bb;
    const float* sa = sA + b * OD_ + o * 32;
    const float* sb = sB ? sB + b * OD_ + o * 32 : nullptr;
    const float* bp = bias + o * 32;
#pragma unroll
    for (int d = 0; d < 16; ++d) {
      float bs0 = bp[d], bs1 = bp[d + 16];
      float va = squashf(sa[d] * scaleA + bs0);
      float vb = squashf(sa[d + 16] * scaleA + bs1);
      if (sb) { va += squashf(sb[d] + bs0); vb += squashf(sb[d + 16] + bs1); }
      vvA[bb][d] = va; vvB[bb][d] = vb;
    }
  }

  float accA[2][16], accB[2][16];
#pragma unroll
  for (int bb = 0; bb < 2; ++bb)
#pragma unroll
    for (int d = 0; d < 16; ++d) { accA[bb][d] = 0.f; accB[bb][d] = 0.f; }

  // ---- staging: wave stages 8 o-slices (1 KB each) of a 64KB half ----
#define STAGE_HALF(row, half, buf)                                         \
  {                                                                        \
    _Pragma("unroll")                                                      \
    for (int k = 0; k < 8; ++k) {                                          \
      const int oo = wv + k * 8;                                           \
      const float* g = (row) + oo * 512 + (half) * 256 + (t & 63) * 4;     \
      gload16(g, (void*)((char*)(buf) + (size_t)(oo * 65) * 16));          \
    }                                                                      \
  }

  // prologue: A(0) staged+drained (sync also covers x staging); B(0) in flight
  const float* Wrow0 = W + (size_t)i0 * (OD_ * 16);
  STAGE_HALF(Wrow0, 0, bufA);
  __syncthreads();
  STAGE_HALF(Wrow0, 1, bufB);

  for (int ii = 0; ii < 8; ++ii) {
    const int i = i0 + ii;
    const float* Wnext = W + (size_t)(i + 1) * (OD_ * 16);

    // x from LDS (broadcast reads, wave-uniform) -> SGPRs
    float xsv[2][16];
#pragma unroll
    for (int bb = 0; bb < 2; ++bb) {
      const float* xp = xls + (size_t)ii * 256 + (wv * 2 + bb) * 16;
#pragma unroll
      for (int k = 0; k < 16; ++k) xsv[bb][k] = rfl(xp[k]);
    }

    float lg[2] = {0.f, 0.f};
    float uA[2][16], uB[2][16];

    // ---- compute half A (d = 0..15) from bufA ----
#pragma unroll
    for (int d = 0; d < 16; ++d) {
      const float4* wp = bufA + o * 65 + d * 4;
      float4 w0 = wp[0], w1 = wp[1], w2 = wp[2], w3 = wp[3];
#pragma unroll
      for (int bb = 0; bb < 2; ++bb) {
        float uu = xsv[bb][0] * w0.x;
        uu = fmaf(xsv[bb][1], w0.y, uu); uu = fmaf(xsv[bb][2], w0.z, uu);
        uu = fmaf(xsv[bb][3], w0.w, uu); uu = fmaf(xsv[bb][4], w1.x, uu);
        uu = fmaf(xsv[bb][5], w1.y, uu); uu = fmaf(xsv[bb][6], w1.z, uu);
        uu = fmaf(xsv[bb][7], w1.w, uu); uu = fmaf(xsv[bb][8], w2.x, uu);
        uu = fmaf(xsv[bb][9], w2.y, uu); uu = fmaf(xsv[bb][10], w2.z, uu);
        uu = fmaf(xsv[bb][11], w2.w, uu); uu = fmaf(xsv[bb][12], w3.x, uu);
        uu = fmaf(xsv[bb][13], w3.y, uu); uu = fmaf(xsv[bb][14], w3.z, uu);
        uu = fmaf(xsv[bb][15], w3.w, uu);
        uA[bb][d] = uu;
        lg[bb] = fmaf(uu, vvA[bb][d], lg[bb]);
      }
    }
    __syncthreads();                 // bufB(ii) complete; all done with bufA
    if (ii < 7) STAGE_HALF(Wnext, 0, bufA);

    // ---- compute half B (d = 16..31) from bufB ----
#pragma unroll
    for (int d = 0; d < 16; ++d) {
      const float4* wp = bufB + o * 65 + d * 4;
      float4 w0 = wp[0], w1 = wp[1], w2 = wp[2], w3 = wp[3];
#pragma unroll
      for (int bb = 0; bb < 2; ++bb) {
        float uu = xsv[bb][0] * w0.x;
        uu = fmaf(xsv[bb][1], w0.y, uu); uu = fmaf(xsv[bb][2], w0.z, uu);
        uu = fmaf(xsv[bb][3], w0.w, uu); uu = fmaf(xsv[bb][4], w1.x, uu);
        uu = fmaf(xsv[bb][5], w1.y, uu); uu = fmaf(xsv[bb][6], w1.z, uu);
        uu = fmaf(xsv[bb][7], w1.w, uu); uu = fmaf(xsv[bb][8], w2.x, uu);
        uu = fmaf(xsv[bb][9], w2.y, uu); uu = fmaf(xsv[bb][10], w2.z, uu);
        uu = fmaf(xsv[bb][11], w2.w, uu); uu = fmaf(xsv[bb][12], w3.x, uu);
        uu = fmaf(xsv[bb][13], w3.y, uu); uu = fmaf(xsv[bb][14], w3.z, uu);
        uu = fmaf(xsv[bb][15], w3.w, uu);
        uB[bb][d] = uu;
        lg[bb] = fmaf(uu, vvB[bb][d], lg[bb]);
      }
    }

    // ---- exact softmax over o (64 lanes) per bb, then accumulate ----
#pragma unroll
    for (int bb = 0; bb < 2; ++bb) {
      float m = lg[bb];
#pragma unroll
      for (int off = 32; off > 0; off >>= 1) m = fmaxf(m, __shfl_xor(m, off, 64));
      float ex = __expf(lg[bb] - m);
      float sm = ex;
#pragma unroll
      for (int off = 32; off > 0; off >>= 1) sm += __shfl_xor(sm, off, 64);
      float c = ex * __builtin_amdgcn_rcpf(sm);
#pragma unroll
      for (int d = 0; d < 16; ++d) {
        accA[bb][d] = fmaf(c, uA[bb][d], accA[bb][d]);
        accB[bb][d] = fmaf(c, uB[bb][d], accB[bb][d]);
      }
    }
    __syncthreads();                 // bufA(ii+1) complete; all done with bufB
    if (ii < 7) STAGE_HALF(Wnext, 1, bufB);
  }

  // ---- write per-(wave,b) partial: part[(b*256 + blk)][o*32 + d] ----
#pragma unroll
  for (int bb = 0; bb < 2; ++bb) {
    const int b = wv * 2 + bb;
    float4* dst = (float4*)(part + ((size_t)(b * 256 + blockIdx.x)) * OD_ + o * 32);
#pragma unroll
    for (int q = 0; q < 4; ++q) {
      float4 v0, v1;
      v0.x = accA[bb][q * 4 + 0]; v0.y = accA[bb][q * 4 + 1];
      v0.z = accA[bb][q * 4 + 2]; v0.w = accA[bb][q * 4 + 3];
      v1.x = accB[bb][q * 4 + 0]; v1.y = accB[bb][q * 4 + 1];
      v1.z = accB[bb][q * 4 + 2]; v1.w = accB[bb][q * 4 + 3];
      dst[q] = v0; dst[q + 4] = v1;
    }
  }
}

// ---------------------------------------------------------------------------
// K4: s1[b,od] = sum_g part[(b*256+g)][od].  grid=256 (16 b x 16 slices).
// ---------------------------------------------------------------------------
__global__ __launch_bounds__(128) void k_s1red(
    const float* __restrict__ part, float* __restrict__ s1)
{
  const int b = blockIdx.x >> 4;
  const int od = (blockIdx.x & 15) * 128 + threadIdx.x;
  float a = 0.f;
  const float* p = part + (size_t)b * 256 * OD_ + od;
#pragma unroll 8
  for (int g = 0; g < 256; ++g) a += p[(size_t)g * OD_];
  s1[b * OD_ + od] = a;
}

// ---------------------------------------------------------------------------
// K5: out[b,od] = squash(sum_g part2 + bias).  grid=256.
// ---------------------------------------------------------------------------
__global__ __launch_bounds__(128) void k_outred(
    const float* __restrict__ part, const float* __restrict__ bias,
    float* __restrict__ out)
{
  const int b = blockIdx.x >> 4;
  const int od = (blockIdx.x & 15) * 128 + threadIdx.x;
  float a = 0.f;
  const float* p = part + (size_t)b * 256 * OD_ + od;
#pragma unroll 8
  for (int g = 0; g < 256; ++g) a += p[(size_t)g * OD_];
  out[b * OD_ + od] = squashf(a + bias[od]);
}

extern "C" void kernel_launch(void* const* d_in, const int* in_sizes, int n_in,
                              void* d_out, int out_size, void* d_ws, size_t ws_size,
                              hipStream_t stream) {
  const float* x = (const float*)d_in[0];
  const float* W = (const float*)d_in[1];
  const float* bias = (const float*)d_in[2];
  float* out = (float*)d_out;

  char* ws = (char*)d_ws;
  float* part0 = (float*)ws;                          // 32 MB s0 partials
  float* part1 = (float*)(ws + 33554432ull);          // 32 MB route partials
  float* part2 = part0;                               // reuse: part0 dead after K2
  float* s0    = (float*)(ws + 67108864ull);          // 128 KB
  float* s1    = s0 + 32768;                          // 128 KB

  k_s0sweep<<<dim3(2048), dim3(256), 0, stream>>>(x, W, part0);
  k_s0red  <<<dim3(256),  dim3(128), 0, stream>>>(part0, s0);
  // pass1: v0 = squash(s0/64 + bias)
  k_rsweep <<<dim3(256),  dim3(512), 0, stream>>>(x, W, s0, 1.0f / 64.0f, nullptr, bias, part1);
  k_s1red  <<<dim3(256),  dim3(128), 0, stream>>>(part1, s1);
  // pass2: vv = squash(s0/64+bias) + squash(s1+bias)
  k_rsweep <<<dim3(256),  dim3(512), 0, stream>>>(x, W, s0, 1.0f / 64.0f, s1, bias, part2);
  k_outred <<<dim3(256),  dim3(128), 0, stream>>>(part2, bias, out);
}